// Round 1
// baseline (186.645 us; speedup 1.0000x reference)
//
#include <hip/hip_runtime.h>
#include <stdint.h>

typedef __bf16 bf16_t;
typedef __bf16 bf16x8 __attribute__((ext_vector_type(8)));
typedef float  f32x4  __attribute__((ext_vector_type(4)));
typedef unsigned long long u64x2 __attribute__((ext_vector_type(2)));

#define SD 296   // LDS row stride in bf16 elements (288 data + 8 pad)

// Repack weights into bf16, K-layout matched to the GEMM kernel:
// K global = ci*288 + (fc*8 + j)   [spline part, 256 slots]
//          = ci*288 + 256 + fc     [silu/base part, 32 slots]
// ci = 0..17: conv tap kpos = ci>>1, channel base c0 = (ci&1)*32
// reference f = c*9 + kpos
__global__ __launch_bounds__(256) void prep_w_kernel(
    const float* __restrict__ bw, const float* __restrict__ sw,
    const float* __restrict__ ss, bf16_t* __restrict__ Wf) {
  int idx = blockIdx.x * 256 + threadIdx.x;
  if (idx >= 64 * 5184) return;
  int o  = idx / 5184;
  int kk = idx - o * 5184;
  int ci  = kk / 288;
  int loc = kk - ci * 288;
  int kpos = ci >> 1;
  int c0 = (ci & 1) * 32;
  float v;
  if (loc < 256) {
    int fc = loc >> 3; int j = loc & 7;
    int f = (c0 + fc) * 9 + kpos;
    v = sw[(o * 576 + f) * 8 + j] * ss[o * 576 + f];
  } else {
    int fc = loc - 256;
    int f = (c0 + fc) * 9 + kpos;
    v = bw[o * 576 + f];
  }
  Wf[idx] = (bf16_t)v;
}

__global__ __launch_bounds__(256) void convkan_kernel(
    const float* __restrict__ X, const bf16_t* __restrict__ Wf,
    float* __restrict__ out) {
  __shared__ bf16_t P[64 * SD];   // 37,888 B

  const int t    = threadIdx.x;
  const int lane = t & 63;
  const int wid  = t >> 6;
  const int n0   = blockIdx.x * 64;      // 64 spatial rows per block
  const int bimg = n0 >> 12;             // image index (4096 pos / image)

  // staging roles: 32 f's per chunk, each thread owns 1 f x 8 rows (stride-8)
  const int fc = t >> 3;      // 0..31  channel-within-chunk
  const int wb = t & 7;       // row offset within stride-8 groups

  const float h    = 0.4f;
  const float G0   = -3.0f * h - 1.0f;   // -2.2
  const float G1   =  8.0f * h - 1.0f;   //  2.2
  const float INVH = 1.0f / h;

  f32x4 acc[4];
  #pragma unroll
  for (int i = 0; i < 4; ++i) acc[i] = (f32x4)0.0f;

  const int rowRd = wid * 16 + (lane & 15);   // A-frag row (spatial)
  const int kRd   = (lane >> 4) * 8;          // A/B-frag k offset

  for (int ci = 0; ci < 18; ++ci) {
    int kpos = ci >> 1;
    int ki = kpos / 3, kj = kpos - ki * 3;
    int c  = (ci & 1) * 32 + fc;

    #pragma unroll
    for (int r = 0; r < 8; ++r) {
      int row = r * 8 + wb;
      int n   = n0 + row;
      int rem = n & 4095;
      int oh = rem >> 6, ow = rem & 63;
      int ih = oh + ki - 1, iw = ow + kj - 1;
      bool ok = (ih >= 0) & (ih < 64) & (iw >= 0) & (iw < 64);
      float x = 0.0f;
      if (ok) x = X[(((bimg * 64 + c) * 64 + ih) << 6) + iw];

      // SiLU
      float sl = x / (1.0f + __expf(-x));

      // uniform cubic B-spline: 4 nonzero taps at j = i0-3 .. i0
      float tt = (x - G0) * INVH;
      int  i0  = (int)tt;
      i0 = i0 < 0 ? 0 : (i0 > 10 ? 10 : i0);
      float u  = tt - (float)i0;
      float um = 1.0f - u;
      float u2 = u * u, u3 = u2 * u;
      float w0 = um * um * um * (1.0f / 6.0f);
      float w1 = (3.0f * u3 - 6.0f * u2 + 4.0f) * (1.0f / 6.0f);
      float w2 = (-3.0f * u3 + 3.0f * u2 + 3.0f * u + 1.0f) * (1.0f / 6.0f);
      float w3 = u3 * (1.0f / 6.0f);
      bool inr = (x >= G0) & (x < G1);

      union { bf16_t hh[4]; unsigned long long u64; } pk;
      pk.hh[0] = (bf16_t)w0; pk.hh[1] = (bf16_t)w1;
      pk.hh[2] = (bf16_t)w2; pk.hh[3] = (bf16_t)w3;
      unsigned long long a = inr ? pk.u64 : 0ull;

      // place 4 bf16 taps at slot j0 = i0-3 within 8-slot (128-bit) window
      int sh = (i0 - 3) * 16;
      unsigned long long lo, hi;
      if (sh >= 0) {
        lo = (sh < 64) ? (a << (sh & 63)) : 0ull;
        hi = (sh == 0) ? 0ull
             : ((sh < 64) ? (a >> ((64 - sh) & 63)) : (a << ((sh - 64) & 63)));
      } else {
        lo = a >> ((-sh) & 63);
        hi = 0ull;
      }
      u64x2 wr; wr.x = lo; wr.y = hi;
      *(u64x2*)&P[row * SD + fc * 8] = wr;         // 8 spline slots, 16B
      P[row * SD + 256 + fc] = (bf16_t)sl;         // silu slot
    }
    __syncthreads();

    // MFMA over this chunk: K = 288 -> 9 steps of 32
    int kbase = ci * 288;
    #pragma unroll
    for (int ks = 0; ks < 9; ++ks) {
      bf16x8 af = *(const bf16x8*)&P[rowRd * SD + ks * 32 + kRd];
      #pragma unroll
      for (int ot = 0; ot < 4; ++ot) {
        int o = ot * 16 + (lane & 15);
        bf16x8 bfrag = *(const bf16x8*)&Wf[o * 5184 + kbase + ks * 32 + kRd];
        acc[ot] = __builtin_amdgcn_mfma_f32_16x16x32_bf16(af, bfrag, acc[ot], 0, 0, 0);
      }
    }
    __syncthreads();
  }

  // store: D col = out-channel (lane&15), row = spatial (lane>>4)*4 + reg
  int nb   = n0 + wid * 16 + (lane >> 4) * 4;
  int nrem = nb & 4095;
  #pragma unroll
  for (int ot = 0; ot < 4; ++ot) {
    int o = ot * 16 + (lane & 15);
    *(f32x4*)&out[((bimg * 64 + o) << 12) + nrem] = acc[ot];
  }
}

extern "C" void kernel_launch(void* const* d_in, const int* in_sizes, int n_in,
                              void* d_out, int out_size, void* d_ws, size_t ws_size,
                              hipStream_t stream) {
  const float* x  = (const float*)d_in[0];
  const float* bw = (const float*)d_in[1];
  const float* sw = (const float*)d_in[2];
  const float* ss = (const float*)d_in[3];
  bf16_t* Wf = (bf16_t*)d_ws;            // 64*5184*2 = 663,552 B
  float* o   = (float*)d_out;

  prep_w_kernel<<<(64 * 5184 + 255) / 256, 256, 0, stream>>>(bw, sw, ss, Wf);
  convkan_kernel<<<512, 256, 0, stream>>>(x, Wf, o);
}